// Round 1
// baseline (3148.251 us; speedup 1.0000x reference)
//
#include <hip/hip_runtime.h>
#include <cstdint>
#include <cstddef>

#define B_    16
#define CIN_  32
#define COUT_ 64
#define N_    1024
#define T_    24
#define SD_   16
#define DD_   16

#define NT_      (N_*T_)          // 24576
#define BNT_     (B_*N_*T_)       // 393216
#define UE_COLS  (B_*T_*SD_)      // 6144
#define XS_COLS  (B_*COUT_*T_)    // 24576

// ---- workspace byte offsets (all 512B aligned) ----
#define OFF_DELAY 0ul                    // fp32 N*T            = 98304 B
#define OFF_M     98304ul                // fp32 N*COUT         = 262144 B
#define OFF_R     360448ul               // fp32 N              = 4096 B
#define OFF_U     364544ul               // fp32 B*N*T          = 1572864 B
#define OFF_UE    1937408ul              // bf16 N*6144         = 12582912 B
#define OFF_P     14520320ul             // bf16 N*6144         = 12582912 B
#define OFF_XS    27103232ul             // bf16 N*24576        = 50331648 B
#define OFF_Y1    77434880ul             // bf16 N*24576
#define OFF_Y2    127766528ul            // bf16 N*24576  (end 178098176)

__device__ __forceinline__ float bfb2f(unsigned short h) {
  union { unsigned u; float f; } v; v.u = ((unsigned)h) << 16; return v.f;
}
__device__ __forceinline__ unsigned short f2bfb(float f) {
  union { float f; unsigned u; } v; v.f = f;
  unsigned u = v.u;
  return (unsigned short)((u + 0x7fffu + ((u >> 16) & 1u)) >> 16);
}
__device__ __forceinline__ float sigm_(float z) { return 1.f / (1.f + expf(-z)); }

// ---------------------------------------------------------------------------
// k_pre: delay[n,t] = sigmoid(tanh(CD@Wd)); M[n,c] = sum_e CS[n,e]*W_mii[c,e];
//        R[n] = rowsum(adj)
// ---------------------------------------------------------------------------
__global__ __launch_bounds__(256) void k_pre(
    const float* __restrict__ CD, const float* __restrict__ Wd,
    const float* __restrict__ CS, const float* __restrict__ W_mii,
    const float* __restrict__ adj,
    float* __restrict__ delay, float* __restrict__ Mbuf, float* __restrict__ Rbuf)
{
  int idx = blockIdx.x * 256 + threadIdx.x;
  if (idx < NT_) {
    int n = idx / T_, t = idx % T_;
    float z = 0.f;
    #pragma unroll
    for (int d = 0; d < DD_; ++d) z += CD[n*DD_ + d] * Wd[d*T_ + t];
    delay[idx] = sigm_(tanhf(z));
  }
  int i2 = idx - NT_;
  if (i2 >= 0 && i2 < N_*COUT_) {
    int n = i2 / COUT_, c = i2 % COUT_;
    float z = 0.f;
    #pragma unroll
    for (int e = 0; e < SD_; ++e) z += CS[n*SD_ + e] * W_mii[c*SD_ + e];
    Mbuf[i2] = z;
  }
  int i3 = idx - NT_ - N_*COUT_;
  if (i3 >= 0 && i3 < N_) {
    const float* row = adj + (size_t)i3 * N_;
    float s = 0.f;
    for (int m = 0; m < N_; ++m) s += row[m];
    Rbuf[i3] = s;
  }
}

// ---------------------------------------------------------------------------
// k_u: u[b,n,t] = b_pro + sum_i W_pro[i]*x[b,i,n,t];  Ue[n][(b*T+t)*16+e] = u*CS[n,e]
// ---------------------------------------------------------------------------
__global__ __launch_bounds__(256) void k_u(
    const float* __restrict__ x, const float* __restrict__ W_pro,
    const float* __restrict__ b_pro, const float* __restrict__ CS,
    float* __restrict__ u, unsigned short* __restrict__ Ue)
{
  int idx = blockIdx.x * 256 + threadIdx.x;
  if (idx >= BNT_) return;
  int t = idx % T_;
  int n = (idx / T_) % N_;
  int b = idx / (T_ * N_);
  const float* xp = x + ((size_t)b * CIN_ * N_ + n) * T_ + t;
  float z = b_pro[0];
  #pragma unroll
  for (int i = 0; i < CIN_; ++i) z += W_pro[i] * xp[(size_t)i * NT_];
  u[idx] = z;
  unsigned short* up = Ue + (size_t)n * UE_COLS + (b * T_ + t) * SD_;
  #pragma unroll
  for (int e = 0; e < SD_; ++e) up[e] = f2bfb(z * CS[n*SD_ + e]);
}

// ---------------------------------------------------------------------------
// k_mm: C[r][c] = sum_k A[r][k]*B[k][c]; A fp32 (1024 x 1024), B bf16 (1024 x ncols)
// MODE 0: C = acc;  MODE 1: C = 2*acc - aux  (for Y2 = 2*S@Y1 - XS)
// 128x128 tile, BK=8, 256 threads, 8x8 per thread.
// ---------------------------------------------------------------------------
template<int MODE>
__global__ __launch_bounds__(256) void k_mm(
    const float* __restrict__ A, const unsigned short* __restrict__ Bm,
    unsigned short* __restrict__ C, const unsigned short* __restrict__ aux,
    int ncols)
{
  __shared__ float As[8][132];
  __shared__ float Bs[8][132];
  const int tid  = threadIdx.x;
  const int row0 = blockIdx.y * 128;
  const int col0 = blockIdx.x * 128;
  const int ty = tid >> 4, tx = tid & 15;
  const int am = tid >> 1, ak = (tid & 1) * 4;
  const int bk = tid >> 5, bc = (tid & 31) * 4;
  float acc[8][8];
  #pragma unroll
  for (int i = 0; i < 8; ++i)
    #pragma unroll
    for (int j = 0; j < 8; ++j) acc[i][j] = 0.f;

  for (int kb = 0; kb < 1024; kb += 8) {
    float4 av = *(const float4*)(A + (size_t)(row0 + am) * 1024 + kb + ak);
    As[ak + 0][am] = av.x; As[ak + 1][am] = av.y;
    As[ak + 2][am] = av.z; As[ak + 3][am] = av.w;
    ushort4 bv = *(const ushort4*)(Bm + (size_t)(kb + bk) * ncols + col0 + bc);
    Bs[bk][bc + 0] = bfb2f(bv.x); Bs[bk][bc + 1] = bfb2f(bv.y);
    Bs[bk][bc + 2] = bfb2f(bv.z); Bs[bk][bc + 3] = bfb2f(bv.w);
    __syncthreads();
    #pragma unroll
    for (int k = 0; k < 8; ++k) {
      float4 a0 = *(const float4*)&As[k][ty * 4];
      float4 a1 = *(const float4*)&As[k][64 + ty * 4];
      float4 b0 = *(const float4*)&Bs[k][tx * 4];
      float4 b1 = *(const float4*)&Bs[k][64 + tx * 4];
      float a[8] = {a0.x,a0.y,a0.z,a0.w,a1.x,a1.y,a1.z,a1.w};
      float b[8] = {b0.x,b0.y,b0.z,b0.w,b1.x,b1.y,b1.z,b1.w};
      #pragma unroll
      for (int i = 0; i < 8; ++i)
        #pragma unroll
        for (int j = 0; j < 8; ++j) acc[i][j] += a[i] * b[j];
    }
    __syncthreads();
  }
  #pragma unroll
  for (int i = 0; i < 8; ++i) {
    int r = row0 + ((i < 4) ? (ty * 4 + i) : (64 + ty * 4 + (i - 4)));
    #pragma unroll
    for (int half = 0; half < 2; ++half) {
      int cb = col0 + half * 64 + tx * 4;
      float v0 = acc[i][half*4+0], v1 = acc[i][half*4+1];
      float v2 = acc[i][half*4+2], v3 = acc[i][half*4+3];
      if (MODE == 1) {
        const unsigned short* ap = aux + (size_t)r * ncols + cb;
        v0 = 2.f*v0 - bfb2f(ap[0]); v1 = 2.f*v1 - bfb2f(ap[1]);
        v2 = 2.f*v2 - bfb2f(ap[2]); v3 = 2.f*v3 - bfb2f(ap[3]);
      }
      ushort4 o; o.x = f2bfb(v0); o.y = f2bfb(v1); o.z = f2bfb(v2); o.w = f2bfb(v3);
      *(ushort4*)(C + (size_t)r * ncols + cb) = o;
    }
  }
}

// ---------------------------------------------------------------------------
// k_attn: one block per (b,n). Fuses D, Q/K/V_t, attn-T, +x_input1, conv_t,
// S recombination, Q/K/V_s, attn-S. Writes XS bf16 in layout [n][b][c][t].
// ---------------------------------------------------------------------------
__global__ __launch_bounds__(256) void k_attn(
    const float* __restrict__ x,
    const float* __restrict__ delay, const float* __restrict__ Mbuf,
    const float* __restrict__ Rbuf, const float* __restrict__ u,
    const unsigned short* __restrict__ P,
    const float* __restrict__ W_de, const float* __restrict__ b_de,
    const float* __restrict__ W_mii, const float* __restrict__ b_mii,
    const float* __restrict__ W_1, const float* __restrict__ b_1,
    const float* __restrict__ Wq_t, const float* __restrict__ bq_t,
    const float* __restrict__ Wk_t, const float* __restrict__ bk_t,
    const float* __restrict__ Wv_t, const float* __restrict__ bv_t,
    const float* __restrict__ W_c1, const float* __restrict__ b_c1,
    const float* __restrict__ Wq_s, const float* __restrict__ bq_s,
    const float* __restrict__ Wk_s, const float* __restrict__ bk_s,
    const float* __restrict__ Wv_s, const float* __restrict__ bv_s,
    unsigned short* __restrict__ XS)
{
  const int n = blockIdx.x, b = blockIdx.y, tid = threadIdx.x;
  __shared__ float xt[CIN_*T_];
  __shared__ float Dt[COUT_*T_];    // reused as x1t in phase 6
  __shared__ float Qt[COUT_*T_];    // reused as Qs
  __shared__ float Kt[COUT_*T_];    // reused as Ks
  __shared__ float Vt[COUT_*T_];    // reused as Vs
  __shared__ float x1in[COUT_*T_];
  __shared__ float XDt[COUT_*T_];
  __shared__ float St[COUT_*T_];
  __shared__ float sc[T_][T_+1];
  __shared__ float Pt[T_][SD_];
  __shared__ float urow[T_];

  for (int i = tid; i < CIN_*T_; i += 256) {
    int ci = i / T_, t = i % T_;
    xt[i] = x[(((size_t)b * CIN_ + ci) * N_ + n) * T_ + t];
  }
  for (int i = tid; i < T_*SD_; i += 256)
    Pt[i / SD_][i % SD_] =
        bfb2f(P[(size_t)n * UE_COLS + (b * T_ + (i / SD_)) * SD_ + (i % SD_)]);
  if (tid < T_) urow[tid] = u[((size_t)b * N_ + n) * T_ + tid];
  __syncthreads();

  const int c = tid >> 2, tq = tid & 3;

  // phase 2: Dt, Qt, x1in (from xt) and St (from Pt/urow)
  {
    float aD[6], aQ[6], a1[6];
    #pragma unroll
    for (int m = 0; m < 6; ++m) { aD[m] = b_de[c]; aQ[m] = bq_t[c]; a1[m] = b_1[c]; }
    for (int i = 0; i < CIN_; ++i) {
      float wd = W_de[c*CIN_+i], wq = Wq_t[c*CIN_+i], w1 = W_1[c*CIN_+i];
      #pragma unroll
      for (int m = 0; m < 6; ++m) {
        float xv = xt[i*T_ + tq + 4*m];
        aD[m] += wd * xv; aQ[m] += wq * xv; a1[m] += w1 * xv;
      }
    }
    float sacc[6];
    float Mv = Mbuf[n*COUT_ + c];
    float bm = b_mii[c] * (1.f + Rbuf[n]);
    #pragma unroll
    for (int m = 0; m < 6; ++m) sacc[m] = urow[tq + 4*m] * Mv + bm;
    for (int e = 0; e < SD_; ++e) {
      float w = W_mii[c*SD_ + e];
      #pragma unroll
      for (int m = 0; m < 6; ++m) sacc[m] += w * Pt[tq + 4*m][e];
    }
    #pragma unroll
    for (int m = 0; m < 6; ++m) {
      int t = tq + 4*m;
      Dt[c*T_ + t]   = aD[m] * delay[n*T_ + t];
      Qt[c*T_ + t]   = aQ[m];
      x1in[c*T_ + t] = a1[m];
      St[c*T_ + t]   = sacc[m];
    }
  }
  __syncthreads();

  // phase 3: Kt, Vt from Dt
  {
    float aK[6], aV[6];
    #pragma unroll
    for (int m = 0; m < 6; ++m) { aK[m] = bk_t[c]; aV[m] = bv_t[c]; }
    for (int j = 0; j < COUT_; ++j) {
      float wk = Wk_t[c*COUT_+j], wv = Wv_t[c*COUT_+j];
      #pragma unroll
      for (int m = 0; m < 6; ++m) {
        float dv = Dt[j*T_ + tq + 4*m];
        aK[m] += wk * dv; aV[m] += wv * dv;
      }
    }
    #pragma unroll
    for (int m = 0; m < 6; ++m) { Kt[c*T_ + tq + 4*m] = aK[m]; Vt[c*T_ + tq + 4*m] = aV[m]; }
  }
  __syncthreads();

  // phase 4: scores_t + softmax
  for (int i = tid; i < T_*T_; i += 256) {
    int t = i / T_, s = i % T_;
    float z = 0.f;
    for (int j = 0; j < COUT_; ++j) z += Qt[j*T_ + t] * Kt[j*T_ + s];
    sc[t][s] = 0.125f * z;
  }
  __syncthreads();
  if (tid < T_) {
    float mx = -1e30f;
    for (int s = 0; s < T_; ++s) mx = fmaxf(mx, sc[tid][s]);
    float sm = 0.f;
    for (int s = 0; s < T_; ++s) { float e = expf(sc[tid][s] - mx); sc[tid][s] = e; sm += e; }
    float inv = 1.f / sm;
    for (int s = 0; s < T_; ++s) sc[tid][s] *= inv;
  }
  __syncthreads();

  // phase 5: XDt = x_input1 + A @ V
  {
    float a[6];
    #pragma unroll
    for (int m = 0; m < 6; ++m) a[m] = x1in[c*T_ + tq + 4*m];
    for (int s = 0; s < T_; ++s) {
      float vv = Vt[c*T_ + s];
      #pragma unroll
      for (int m = 0; m < 6; ++m) a[m] += sc[tq + 4*m][s] * vv;
    }
    #pragma unroll
    for (int m = 0; m < 6; ++m) XDt[c*T_ + tq + 4*m] = a[m];
  }
  __syncthreads();

  // phase 6: x1 = conv_t(XD) -> into Dt
  {
    float a[6];
    #pragma unroll
    for (int m = 0; m < 6; ++m) a[m] = b_c1[c];
    for (int i = 0; i < COUT_; ++i) {
      float w0 = W_c1[(c*COUT_+i)*3 + 0];
      float w1 = W_c1[(c*COUT_+i)*3 + 1];
      float w2 = W_c1[(c*COUT_+i)*3 + 2];
      #pragma unroll
      for (int m = 0; m < 6; ++m) {
        int t = tq + 4*m;
        float xm = (t > 0)      ? XDt[i*T_ + t - 1] : 0.f;
        float x0 = XDt[i*T_ + t];
        float xp = (t < T_ - 1) ? XDt[i*T_ + t + 1] : 0.f;
        a[m] += w0 * xm + w1 * x0 + w2 * xp;
      }
    }
    #pragma unroll
    for (int m = 0; m < 6; ++m) Dt[c*T_ + tq + 4*m] = a[m];
  }
  __syncthreads();

  // phase 7: Qs (from x1=Dt), Ks, Vs (from St) -> into Qt,Kt,Vt
  {
    float aq[6], ak2[6], av2[6];
    #pragma unroll
    for (int m = 0; m < 6; ++m) { aq[m] = bq_s[c]; ak2[m] = bk_s[c]; av2[m] = bv_s[c]; }
    for (int j = 0; j < COUT_; ++j) {
      float wq = Wq_s[c*COUT_+j], wk = Wk_s[c*COUT_+j], wv = Wv_s[c*COUT_+j];
      #pragma unroll
      for (int m = 0; m < 6; ++m) {
        float x1v = Dt[j*T_ + tq + 4*m];
        float sv  = St[j*T_ + tq + 4*m];
        aq[m] += wq * x1v; ak2[m] += wk * sv; av2[m] += wv * sv;
      }
    }
    #pragma unroll
    for (int m = 0; m < 6; ++m) {
      Qt[c*T_ + tq + 4*m] = aq[m];
      Kt[c*T_ + tq + 4*m] = ak2[m];
      Vt[c*T_ + tq + 4*m] = av2[m];
    }
  }
  __syncthreads();

  // phase 8: scores_s + softmax
  for (int i = tid; i < T_*T_; i += 256) {
    int t = i / T_, s = i % T_;
    float z = 0.f;
    for (int j = 0; j < COUT_; ++j) z += Qt[j*T_ + t] * Kt[j*T_ + s];
    sc[t][s] = 0.125f * z;
  }
  __syncthreads();
  if (tid < T_) {
    float mx = -1e30f;
    for (int s = 0; s < T_; ++s) mx = fmaxf(mx, sc[tid][s]);
    float sm = 0.f;
    for (int s = 0; s < T_; ++s) { float e = expf(sc[tid][s] - mx); sc[tid][s] = e; sm += e; }
    float inv = 1.f / sm;
    for (int s = 0; s < T_; ++s) sc[tid][s] *= inv;
  }
  __syncthreads();

  // phase 9: XS = A_s @ V_s, write bf16 [n][b][c][t]
  {
    float a[6];
    #pragma unroll
    for (int m = 0; m < 6; ++m) a[m] = 0.f;
    for (int s = 0; s < T_; ++s) {
      float vv = Vt[c*T_ + s];
      #pragma unroll
      for (int m = 0; m < 6; ++m) a[m] += sc[tq + 4*m][s] * vv;
    }
    size_t base = (size_t)n * XS_COLS + ((size_t)b * COUT_ + c) * T_;
    #pragma unroll
    for (int m = 0; m < 6; ++m) XS[base + tq + 4*m] = f2bfb(a[m]);
  }
}

// ---------------------------------------------------------------------------
// k_final: out[b,c,n,t] = (filt + x_input1) * sigmoid(gate)
// filt/gate from W_g over (XS, Y1, Y2); x_input1 recomputed from x.
// ---------------------------------------------------------------------------
__global__ __launch_bounds__(256) void k_final(
    const float* __restrict__ x,
    const unsigned short* __restrict__ XS, const unsigned short* __restrict__ Y1,
    const unsigned short* __restrict__ Y2,
    const float* __restrict__ W_1, const float* __restrict__ b_1,
    const float* __restrict__ W_g, const float* __restrict__ b_g,
    float* __restrict__ out)
{
  const int n = blockIdx.x, b = blockIdx.y, tid = threadIdx.x;
  __shared__ float XSs[COUT_*T_], Y1s[COUT_*T_], Y2s[COUT_*T_];
  __shared__ float x1s[COUT_*T_], xts[CIN_*T_];
  size_t base = (size_t)n * XS_COLS + (size_t)b * COUT_ * T_;
  for (int i = tid; i < COUT_*T_; i += 256) {
    XSs[i] = bfb2f(XS[base + i]);
    Y1s[i] = bfb2f(Y1[base + i]);
    Y2s[i] = bfb2f(Y2[base + i]);
  }
  for (int i = tid; i < CIN_*T_; i += 256) {
    int ci = i / T_, t = i % T_;
    xts[i] = x[(((size_t)b * CIN_ + ci) * N_ + n) * T_ + t];
  }
  __syncthreads();
  const int c = tid >> 2, tq = tid & 3;
  {
    float a[6];
    #pragma unroll
    for (int m = 0; m < 6; ++m) a[m] = b_1[c];
    for (int i = 0; i < CIN_; ++i) {
      float w = W_1[c*CIN_+i];
      #pragma unroll
      for (int m = 0; m < 6; ++m) a[m] += w * xts[i*T_ + tq + 4*m];
    }
    #pragma unroll
    for (int m = 0; m < 6; ++m) x1s[c*T_ + tq + 4*m] = a[m];
  }
  __syncthreads();
  {
    float af[6], ag[6];
    #pragma unroll
    for (int m = 0; m < 6; ++m) { af[m] = b_g[c]; ag[m] = b_g[COUT_ + c]; }
    for (int j = 0; j < COUT_; ++j) {
      const float* wf = W_g + (size_t)c * 192 + 3*j;
      const float* wg = W_g + (size_t)(COUT_ + c) * 192 + 3*j;
      float wf0 = wf[0], wf1 = wf[1], wf2 = wf[2];
      float wg0 = wg[0], wg1 = wg[1], wg2 = wg[2];
      #pragma unroll
      for (int m = 0; m < 6; ++m) {
        int t = tq + 4*m;
        float xs = XSs[j*T_ + t], y1 = Y1s[j*T_ + t], y2 = Y2s[j*T_ + t];
        af[m] += wf0 * xs + wf1 * y1 + wf2 * y2;
        ag[m] += wg0 * xs + wg1 * y1 + wg2 * y2;
      }
    }
    #pragma unroll
    for (int m = 0; m < 6; ++m) {
      int t = tq + 4*m;
      float g = sigm_(ag[m]);
      out[(((size_t)b * COUT_ + c) * N_ + n) * T_ + t] = (af[m] + x1s[c*T_ + t]) * g;
    }
  }
}

// ---------------------------------------------------------------------------
extern "C" void kernel_launch(void* const* d_in, const int* in_sizes, int n_in,
                              void* d_out, int out_size, void* d_ws, size_t ws_size,
                              hipStream_t stream) {
  const float* x        = (const float*)d_in[0];
  const float* supports = (const float*)d_in[1];
  const float* CD       = (const float*)d_in[2];
  const float* CS       = (const float*)d_in[3];
  const float* adj      = (const float*)d_in[4];
  const float* W_de  = (const float*)d_in[5];  const float* b_de  = (const float*)d_in[6];
  const float* Wd    = (const float*)d_in[7];
  const float* W_pro = (const float*)d_in[8];  const float* b_pro = (const float*)d_in[9];
  const float* W_mii = (const float*)d_in[10]; const float* b_mii = (const float*)d_in[11];
  const float* W_1   = (const float*)d_in[12]; const float* b_1   = (const float*)d_in[13];
  const float* Wq_t  = (const float*)d_in[14]; const float* bq_t  = (const float*)d_in[15];
  const float* Wk_t  = (const float*)d_in[16]; const float* bk_t  = (const float*)d_in[17];
  const float* Wv_t  = (const float*)d_in[18]; const float* bv_t  = (const float*)d_in[19];
  const float* W_c1  = (const float*)d_in[20]; const float* b_c1  = (const float*)d_in[21];
  const float* Wq_s  = (const float*)d_in[22]; const float* bq_s  = (const float*)d_in[23];
  const float* Wk_s  = (const float*)d_in[24]; const float* bk_s  = (const float*)d_in[25];
  const float* Wv_s  = (const float*)d_in[26]; const float* bv_s  = (const float*)d_in[27];
  const float* W_g   = (const float*)d_in[28]; const float* b_g   = (const float*)d_in[29];
  float* out = (float*)d_out;

  char* ws = (char*)d_ws;
  float*          delay = (float*)(ws + OFF_DELAY);
  float*          Mbuf  = (float*)(ws + OFF_M);
  float*          Rbuf  = (float*)(ws + OFF_R);
  float*          u     = (float*)(ws + OFF_U);
  unsigned short* Ue    = (unsigned short*)(ws + OFF_UE);
  unsigned short* P     = (unsigned short*)(ws + OFF_P);
  unsigned short* XS    = (unsigned short*)(ws + OFF_XS);
  unsigned short* Y1    = (unsigned short*)(ws + OFF_Y1);
  unsigned short* Y2    = (unsigned short*)(ws + OFF_Y2);

  (void)in_sizes; (void)n_in; (void)out_size; (void)ws_size;

  // 1) small precompute
  k_pre<<<dim3((NT_ + N_*COUT_ + N_ + 255) / 256), 256, 0, stream>>>(
      CD, Wd, CS, W_mii, adj, delay, Mbuf, Rbuf);
  // 2) u + Ue
  k_u<<<dim3((BNT_ + 255) / 256), 256, 0, stream>>>(x, W_pro, b_pro, CS, u, Ue);
  // 3) P = adj @ Ue   (1024 x 6144)
  k_mm<0><<<dim3(UE_COLS / 128, N_ / 128), 256, 0, stream>>>(adj, Ue, P, nullptr, UE_COLS);
  // 4) fused attention pipeline -> XS
  k_attn<<<dim3(N_, B_), 256, 0, stream>>>(
      x, delay, Mbuf, Rbuf, u, P,
      W_de, b_de, W_mii, b_mii, W_1, b_1,
      Wq_t, bq_t, Wk_t, bk_t, Wv_t, bv_t,
      W_c1, b_c1, Wq_s, bq_s, Wk_s, bk_s, Wv_s, bv_s, XS);
  // 5) Y1 = supports @ XS
  k_mm<0><<<dim3(XS_COLS / 128, N_ / 128), 256, 0, stream>>>(supports, XS, Y1, nullptr, XS_COLS);
  // 6) Y2 = 2*supports @ Y1 - XS  (== L2 @ XS)
  k_mm<1><<<dim3(XS_COLS / 128, N_ / 128), 256, 0, stream>>>(supports, Y1, Y2, XS, XS_COLS);
  // 7) final gating
  k_final<<<dim3(N_, B_), 256, 0, stream>>>(x, XS, Y1, Y2, W_1, b_1, W_g, b_g, out);
}

// Round 2
// 1851.986 us; speedup vs baseline: 1.6999x; 1.6999x over previous
//
#include <hip/hip_runtime.h>
#include <cstdint>
#include <cstddef>

#define B_    16
#define CIN_  32
#define COUT_ 64
#define N_    1024
#define T_    24
#define SD_   16
#define DD_   16

#define NT_      (N_*T_)          // 24576
#define BNT_     (B_*N_*T_)       // 393216
#define UE_COLS  (B_*T_*SD_)      // 6144
#define XS_COLS  (B_*COUT_*T_)    // 24576
#define HALF_COLS (XS_COLS/2)     // 12288

typedef unsigned short ushort_t;
using bf16x8 = __attribute__((ext_vector_type(8))) short;
using f32x4  = __attribute__((ext_vector_type(4))) float;

// ---- workspace byte offsets ----
#define OFF_DELAY 0ul                    // fp32 24576
#define OFF_M     98304ul                // fp32 65536
#define OFF_R     360448ul               // fp32 1024
#define OFF_U     364544ul               // fp32 393216
#define OFF_WDET  1937408ul              // fp32 2048
#define OFF_WQTT  1945600ul
#define OFF_W1T   1953792ul
#define OFF_WMIIT 1961984ul              // fp32 1024
#define OFF_WKTT  1966080ul              // fp32 4096
#define OFF_WVTT  1982464ul
#define OFF_WQST  1998848ul
#define OFF_WKST  2015232ul
#define OFF_WVST  2031616ul
#define OFF_WC1T  2048000ul              // fp32 12288
#define OFF_WGT   2097152ul              // fp32 24576
#define OFF_SBF   2195456ul              // bf16 1M
#define OFF_ADJBF 4292608ul
#define OFF_STBF  6389760ul
#define OFF_L2BF  8486912ul
#define OFF_X1    10584064ul             // Ue then P (bf16 1024*6144)
#define OFF_X2    23166976ul             // UeT (12.6MB) then XST_h (25.2MB)
#define OFF_XS    48332800ul             // bf16 1024*24576
#define OFF_Y1H   98664448ul             // bf16 1024*12288
#define OFF_Y2H   123830272ul            // bf16 1024*12288  (end ~149 MB)

__device__ __forceinline__ float bfb2f(ushort_t h) {
  union { unsigned u; float f; } v; v.u = ((unsigned)h) << 16; return v.f;
}
__device__ __forceinline__ ushort_t f2bfb(float f) {
  union { float f; unsigned u; } v; v.f = f;
  unsigned u = v.u;
  return (ushort_t)((u + 0x7fffu + ((u >> 16) & 1u)) >> 16);
}
__device__ __forceinline__ float sigm_(float z) { return 1.f / (1.f + expf(-z)); }

__device__ __forceinline__ void gl_lds16(const ushort_t* g, ushort_t* l) {
  __builtin_amdgcn_global_load_lds(
      (const __attribute__((address_space(1))) unsigned int*)g,
      (__attribute__((address_space(3))) unsigned int*)l, 16, 0, 0);
}

// ---------------------------------------------------------------------------
// k_prep: bf16 conversions of supports/adj, supports^T (bf16), all weight
// transposes (fp32) for coalesced reads in k_attn / k_final.
// ---------------------------------------------------------------------------
__global__ __launch_bounds__(256) void k_prep(
    const float* __restrict__ supports, const float* __restrict__ adj,
    const float* __restrict__ W_de, const float* __restrict__ Wq_t,
    const float* __restrict__ W_1, const float* __restrict__ W_mii,
    const float* __restrict__ Wk_t, const float* __restrict__ Wv_t,
    const float* __restrict__ Wq_s, const float* __restrict__ Wk_s,
    const float* __restrict__ Wv_s, const float* __restrict__ W_c1,
    const float* __restrict__ W_g,
    ushort_t* __restrict__ Sbf, ushort_t* __restrict__ adjbf,
    ushort_t* __restrict__ STbf,
    float* __restrict__ WdeT, float* __restrict__ WqtT, float* __restrict__ W1T,
    float* __restrict__ WmiiT,
    float* __restrict__ WktT, float* __restrict__ WvtT, float* __restrict__ WqsT,
    float* __restrict__ WksT, float* __restrict__ WvsT,
    float* __restrict__ Wc1T, float* __restrict__ WgT)
{
  int idx = blockIdx.x * 256 + threadIdx.x;
  if (idx < N_*N_) {
    Sbf[idx]   = f2bfb(supports[idx]);
    adjbf[idx] = f2bfb(adj[idx]);
    int n = idx >> 10, k = idx & 1023;
    STbf[idx]  = f2bfb(supports[k*N_ + n]);    // STbf[n][k] = S[k][n]
  }
  int j = idx - N_*N_;
  if (j < 0) return;
  if (j < 2048) { int k = j>>6, c = j&63; WdeT[j] = W_de[c*32 + k]; return; }
  j -= 2048;
  if (j < 2048) { int k = j>>6, c = j&63; WqtT[j] = Wq_t[c*32 + k]; return; }
  j -= 2048;
  if (j < 2048) { int k = j>>6, c = j&63; W1T[j] = W_1[c*32 + k]; return; }
  j -= 2048;
  if (j < 1024) { int e = j>>6, c = j&63; WmiiT[j] = W_mii[c*16 + e]; return; }
  j -= 1024;
  if (j < 4096) { int k = j>>6, c = j&63; WktT[j] = Wk_t[c*64 + k]; return; }
  j -= 4096;
  if (j < 4096) { int k = j>>6, c = j&63; WvtT[j] = Wv_t[c*64 + k]; return; }
  j -= 4096;
  if (j < 4096) { int k = j>>6, c = j&63; WqsT[j] = Wq_s[c*64 + k]; return; }
  j -= 4096;
  if (j < 4096) { int k = j>>6, c = j&63; WksT[j] = Wk_s[c*64 + k]; return; }
  j -= 4096;
  if (j < 4096) { int k = j>>6, c = j&63; WvsT[j] = Wv_s[c*64 + k]; return; }
  j -= 4096;
  if (j < 12288) { int g = j>>6, c = j&63; Wc1T[j] = W_c1[c*192 + g]; return; }
  j -= 12288;
  if (j < 24576) { int g = j>>7, cc = j&127; WgT[j] = W_g[cc*192 + g]; return; }
}
#define PREP_TOTAL (N_*N_ + 64512)

// ---------------------------------------------------------------------------
// k_pre: delay, Mbuf, Rbuf (unchanged from R1)
// ---------------------------------------------------------------------------
__global__ __launch_bounds__(256) void k_pre(
    const float* __restrict__ CD, const float* __restrict__ Wd,
    const float* __restrict__ CS, const float* __restrict__ W_mii,
    const float* __restrict__ adj,
    float* __restrict__ delay, float* __restrict__ Mbuf, float* __restrict__ Rbuf)
{
  int idx = blockIdx.x * 256 + threadIdx.x;
  if (idx < NT_) {
    int n = idx / T_, t = idx % T_;
    float z = 0.f;
    #pragma unroll
    for (int d = 0; d < DD_; ++d) z += CD[n*DD_ + d] * Wd[d*T_ + t];
    delay[idx] = sigm_(tanhf(z));
  }
  int i2 = idx - NT_;
  if (i2 >= 0 && i2 < N_*COUT_) {
    int n = i2 / COUT_, c = i2 % COUT_;
    float z = 0.f;
    #pragma unroll
    for (int e = 0; e < SD_; ++e) z += CS[n*SD_ + e] * W_mii[c*SD_ + e];
    Mbuf[i2] = z;
  }
  int i3 = idx - NT_ - N_*COUT_;
  if (i3 >= 0 && i3 < N_) {
    const float* row = adj + (size_t)i3 * N_;
    float s = 0.f;
    for (int m = 0; m < N_; ++m) s += row[m];
    Rbuf[i3] = s;
  }
}

// ---------------------------------------------------------------------------
// k_u: unchanged from R1 (Ue now lives at OFF_X1)
// ---------------------------------------------------------------------------
__global__ __launch_bounds__(256) void k_u(
    const float* __restrict__ x, const float* __restrict__ W_pro,
    const float* __restrict__ b_pro, const float* __restrict__ CS,
    float* __restrict__ u, ushort_t* __restrict__ Ue)
{
  int idx = blockIdx.x * 256 + threadIdx.x;
  if (idx >= BNT_) return;
  int t = idx % T_;
  int n = (idx / T_) % N_;
  int b = idx / (T_ * N_);
  const float* xp = x + ((size_t)b * CIN_ * N_ + n) * T_ + t;
  float z = b_pro[0];
  #pragma unroll
  for (int i = 0; i < CIN_; ++i) z += W_pro[i] * xp[(size_t)i * NT_];
  u[idx] = z;
  ushort_t* up = Ue + (size_t)n * UE_COLS + (b * T_ + t) * SD_;
  #pragma unroll
  for (int e = 0; e < SD_; ++e) up[e] = f2bfb(z * CS[n*SD_ + e]);
}

// ---------------------------------------------------------------------------
// k_tr: bf16 transpose dst[c*R + r] = src[r*sstride + c], tiles 32x32.
// ---------------------------------------------------------------------------
__global__ __launch_bounds__(256) void k_tr(
    const ushort_t* __restrict__ src, ushort_t* __restrict__ dst,
    int R, int sstride)
{
  __shared__ ushort_t tb[32][33];
  const int tid = threadIdx.x;
  const int tx = tid & 31, ty = tid >> 5;          // ty in 0..7
  const int c0 = blockIdx.x * 32, r0 = blockIdx.y * 32;
  #pragma unroll
  for (int p = 0; p < 4; ++p) {
    int r = r0 + ty + p*8;
    tb[ty + p*8][tx] = src[(size_t)r * sstride + c0 + tx];
  }
  __syncthreads();
  #pragma unroll
  for (int p = 0; p < 4; ++p) {
    int c = c0 + ty + p*8;
    dst[(size_t)c * R + r0 + tx] = tb[tx][ty + p*8];
  }
}

// ---------------------------------------------------------------------------
// k_mmx: C[m][col] = sum_k A[m][k] * BT[col][k]; all bf16, fp32 accum.
// A: [1024][1024] row-major. BT: [ncols][1024] row-major. C: [1024][ncols].
// 128x128 tile, BK=64, 4 waves in 2x2, mfma 16x16x32 bf16, XOR-swizzled LDS,
// global_load_lds width-16 staging. MODE 0: plain. MODE 2: D = 2*acc - I.
// ---------------------------------------------------------------------------
template<int MODE>
__global__ __launch_bounds__(256) void k_mmx(
    const ushort_t* __restrict__ Abf, const ushort_t* __restrict__ BT,
    ushort_t* __restrict__ Cc, int ncols)
{
  __shared__ ushort_t As[128*64];
  __shared__ ushort_t Bs[128*64];
  const int tid  = threadIdx.x;
  const int wave = tid >> 6, lane = tid & 63;
  const int row0 = blockIdx.y * 128;
  const int col0 = blockIdx.x * 128;
  const int wm = (wave >> 1) * 64, wn = (wave & 1) * 64;
  const int l15 = lane & 15, quad = lane >> 4, l7 = lane & 7;

  f32x4 acc[4][4];
  #pragma unroll
  for (int i = 0; i < 4; ++i)
    #pragma unroll
    for (int j = 0; j < 4; ++j) acc[i][j] = (f32x4){0.f,0.f,0.f,0.f};

  for (int kb = 0; kb < 1024; kb += 64) {
    #pragma unroll
    for (int p = 0; p < 4; ++p) {
      int chunk = p*256 + tid;
      int r = chunk >> 3, pc = chunk & 7;
      int kc = pc ^ (r & 7);
      gl_lds16(Abf + (size_t)(row0 + r)*1024 + (kb + kc*8), &As[chunk*8]);
    }
    #pragma unroll
    for (int p = 0; p < 4; ++p) {
      int chunk = p*256 + tid;
      int r = chunk >> 3, pc = chunk & 7;
      int kc = pc ^ (r & 7);
      gl_lds16(BT + (size_t)(col0 + r)*1024 + (kb + kc*8), &Bs[chunk*8]);
    }
    __syncthreads();
    #pragma unroll
    for (int kh = 0; kh < 2; ++kh) {
      const int kcb = kh * 4;
      bf16x8 af[4], bfr[4];
      #pragma unroll
      for (int mi = 0; mi < 4; ++mi)
        af[mi] = *(const bf16x8*)&As[(wm + mi*16 + l15)*64 + (((kcb + quad) ^ l7) << 3)];
      #pragma unroll
      for (int ni = 0; ni < 4; ++ni)
        bfr[ni] = *(const bf16x8*)&Bs[(wn + ni*16 + l15)*64 + (((kcb + quad) ^ l7) << 3)];
      #pragma unroll
      for (int mi = 0; mi < 4; ++mi)
        #pragma unroll
        for (int ni = 0; ni < 4; ++ni)
          acc[mi][ni] = __builtin_amdgcn_mfma_f32_16x16x32_bf16(
              af[mi], bfr[ni], acc[mi][ni], 0, 0, 0);
    }
    __syncthreads();
  }

  #pragma unroll
  for (int mi = 0; mi < 4; ++mi) {
    int grow_b = row0 + wm + mi*16 + quad*4;
    #pragma unroll
    for (int ni = 0; ni < 4; ++ni) {
      int gcol = col0 + wn + ni*16 + l15;
      #pragma unroll
      for (int j = 0; j < 4; ++j) {
        float v = acc[mi][ni][j];
        int grow = grow_b + j;
        if (MODE == 2) v = 2.f*v - ((grow == gcol) ? 1.f : 0.f);
        Cc[(size_t)grow * ncols + gcol] = f2bfb(v);
      }
    }
  }
}

// ---------------------------------------------------------------------------
// k_attn: as R1 but all weight reads via transposed (coalesced) arrays.
// ---------------------------------------------------------------------------
__global__ __launch_bounds__(256) void k_attn(
    const float* __restrict__ x,
    const float* __restrict__ delay, const float* __restrict__ Mbuf,
    const float* __restrict__ Rbuf, const float* __restrict__ u,
    const ushort_t* __restrict__ P,
    const float* __restrict__ WdeT, const float* __restrict__ b_de,
    const float* __restrict__ WmiiT, const float* __restrict__ b_mii,
    const float* __restrict__ W1T, const float* __restrict__ b_1,
    const float* __restrict__ WqtT, const float* __restrict__ bq_t,
    const float* __restrict__ WktT, const float* __restrict__ bk_t,
    const float* __restrict__ WvtT, const float* __restrict__ bv_t,
    const float* __restrict__ Wc1T, const float* __restrict__ b_c1,
    const float* __restrict__ WqsT, const float* __restrict__ bq_s,
    const float* __restrict__ WksT, const float* __restrict__ bk_s,
    const float* __restrict__ WvsT, const float* __restrict__ bv_s,
    ushort_t* __restrict__ XS)
{
  const int n = blockIdx.x, b = blockIdx.y, tid = threadIdx.x;
  __shared__ float xt[CIN_*T_];
  __shared__ float Dt[COUT_*T_];
  __shared__ float Qt[COUT_*T_];
  __shared__ float Kt[COUT_*T_];
  __shared__ float Vt[COUT_*T_];
  __shared__ float x1in[COUT_*T_];
  __shared__ float XDt[COUT_*T_];
  __shared__ float St[COUT_*T_];
  __shared__ float sc[T_][T_+1];
  __shared__ float Pt[T_][SD_];
  __shared__ float urow[T_];

  for (int i = tid; i < CIN_*T_; i += 256) {
    int ci = i / T_, t = i % T_;
    xt[i] = x[(((size_t)b * CIN_ + ci) * N_ + n) * T_ + t];
  }
  for (int i = tid; i < T_*SD_; i += 256)
    Pt[i / SD_][i % SD_] =
        bfb2f(P[(size_t)n * UE_COLS + (b * T_ + (i / SD_)) * SD_ + (i % SD_)]);
  if (tid < T_) urow[tid] = u[((size_t)b * N_ + n) * T_ + tid];
  __syncthreads();

  const int c = tid >> 2, tq = tid & 3;

  // phase 2: Dt, Qt, x1in, St
  {
    float aD[6], aQ[6], a1[6];
    #pragma unroll
    for (int m = 0; m < 6; ++m) { aD[m] = b_de[c]; aQ[m] = bq_t[c]; a1[m] = b_1[c]; }
    for (int i = 0; i < CIN_; ++i) {
      float wd = WdeT[i*64+c], wq = WqtT[i*64+c], w1 = W1T[i*64+c];
      #pragma unroll
      for (int m = 0; m < 6; ++m) {
        float xv = xt[i*T_ + tq + 4*m];
        aD[m] += wd * xv; aQ[m] += wq * xv; a1[m] += w1 * xv;
      }
    }
    float sacc[6];
    float Mv = Mbuf[n*COUT_ + c];
    float bm = b_mii[c] * (1.f + Rbuf[n]);
    #pragma unroll
    for (int m = 0; m < 6; ++m) sacc[m] = urow[tq + 4*m] * Mv + bm;
    for (int e = 0; e < SD_; ++e) {
      float w = WmiiT[e*64+c];
      #pragma unroll
      for (int m = 0; m < 6; ++m) sacc[m] += w * Pt[tq + 4*m][e];
    }
    #pragma unroll
    for (int m = 0; m < 6; ++m) {
      int t = tq + 4*m;
      Dt[c*T_ + t]   = aD[m] * delay[n*T_ + t];
      Qt[c*T_ + t]   = aQ[m];
      x1in[c*T_ + t] = a1[m];
      St[c*T_ + t]   = sacc[m];
    }
  }
  __syncthreads();

  // phase 3: Kt, Vt from Dt
  {
    float aK[6], aV[6];
    #pragma unroll
    for (int m = 0; m < 6; ++m) { aK[m] = bk_t[c]; aV[m] = bv_t[c]; }
    for (int j = 0; j < COUT_; ++j) {
      float wk = WktT[j*64+c], wv = WvtT[j*64+c];
      #pragma unroll
      for (int m = 0; m < 6; ++m) {
        float dv = Dt[j*T_ + tq + 4*m];
        aK[m] += wk * dv; aV[m] += wv * dv;
      }
    }
    #pragma unroll
    for (int m = 0; m < 6; ++m) { Kt[c*T_ + tq + 4*m] = aK[m]; Vt[c*T_ + tq + 4*m] = aV[m]; }
  }
  __syncthreads();

  // phase 4: scores_t + softmax
  for (int i = tid; i < T_*T_; i += 256) {
    int t = i / T_, s = i % T_;
    float z = 0.f;
    for (int j = 0; j < COUT_; ++j) z += Qt[j*T_ + t] * Kt[j*T_ + s];
    sc[t][s] = 0.125f * z;
  }
  __syncthreads();
  if (tid < T_) {
    float mx = -1e30f;
    for (int s = 0; s < T_; ++s) mx = fmaxf(mx, sc[tid][s]);
    float sm = 0.f;
    for (int s = 0; s < T_; ++s) { float e = expf(sc[tid][s] - mx); sc[tid][s] = e; sm += e; }
    float inv = 1.f / sm;
    for (int s = 0; s < T_; ++s) sc[tid][s] *= inv;
  }
  __syncthreads();

  // phase 5: XDt = x_input1 + A @ V
  {
    float a[6];
    #pragma unroll
    for (int m = 0; m < 6; ++m) a[m] = x1in[c*T_ + tq + 4*m];
    for (int s = 0; s < T_; ++s) {
      float vv = Vt[c*T_ + s];
      #pragma unroll
      for (int m = 0; m < 6; ++m) a[m] += sc[tq + 4*m][s] * vv;
    }
    #pragma unroll
    for (int m = 0; m < 6; ++m) XDt[c*T_ + tq + 4*m] = a[m];
  }
  __syncthreads();

  // phase 6: x1 = conv_t(XD) -> into Dt
  {
    float a[6];
    #pragma unroll
    for (int m = 0; m < 6; ++m) a[m] = b_c1[c];
    for (int i = 0; i < COUT_; ++i) {
      float w0 = Wc1T[i*192 + c];
      float w1 = Wc1T[i*192 + 64 + c];
      float w2 = Wc1T[i*192 + 128 + c];
      #pragma unroll
      for (int m = 0; m < 6; ++m) {
        int t = tq + 4*m;
        float xm = (t > 0)      ? XDt[i*T_ + t - 1] : 0.f;
        float x0 = XDt[i*T_ + t];
        float xp = (t < T_ - 1) ? XDt[i*T_ + t + 1] : 0.f;
        a[m] += w0 * xm + w1 * x0 + w2 * xp;
      }
    }
    #pragma unroll
    for (int m = 0; m < 6; ++m) Dt[c*T_ + tq + 4*m] = a[m];
  }
  __syncthreads();

  // phase 7: Qs, Ks, Vs
  {
    float aq[6], ak2[6], av2[6];
    #pragma unroll
    for (int m = 0; m < 6; ++m) { aq[m] = bq_s[c]; ak2[m] = bk_s[c]; av2[m] = bv_s[c]; }
    for (int j = 0; j < COUT_; ++j) {
      float wq = WqsT[j*64+c], wk = WksT[j*64+c], wv = WvsT[j*64+c];
      #pragma unroll
      for (int m = 0; m < 6; ++m) {
        float x1v = Dt[j*T_ + tq + 4*m];
        float sv  = St[j*T_ + tq + 4*m];
        aq[m] += wq * x1v; ak2[m] += wk * sv; av2[m] += wv * sv;
      }
    }
    #pragma unroll
    for (int m = 0; m < 6; ++m) {
      Qt[c*T_ + tq + 4*m] = aq[m];
      Kt[c*T_ + tq + 4*m] = ak2[m];
      Vt[c*T_ + tq + 4*m] = av2[m];
    }
  }
  __syncthreads();

  // phase 8: scores_s + softmax
  for (int i = tid; i < T_*T_; i += 256) {
    int t = i / T_, s = i % T_;
    float z = 0.f;
    for (int j = 0; j < COUT_; ++j) z += Qt[j*T_ + t] * Kt[j*T_ + s];
    sc[t][s] = 0.125f * z;
  }
  __syncthreads();
  if (tid < T_) {
    float mx = -1e30f;
    for (int s = 0; s < T_; ++s) mx = fmaxf(mx, sc[tid][s]);
    float sm = 0.f;
    for (int s = 0; s < T_; ++s) { float e = expf(sc[tid][s] - mx); sc[tid][s] = e; sm += e; }
    float inv = 1.f / sm;
    for (int s = 0; s < T_; ++s) sc[tid][s] *= inv;
  }
  __syncthreads();

  // phase 9: XS = A_s @ V_s
  {
    float a[6];
    #pragma unroll
    for (int m = 0; m < 6; ++m) a[m] = 0.f;
    for (int s = 0; s < T_; ++s) {
      float vv = Vt[c*T_ + s];
      #pragma unroll
      for (int m = 0; m < 6; ++m) a[m] += sc[tq + 4*m][s] * vv;
    }
    size_t base = (size_t)n * XS_COLS + ((size_t)b * COUT_ + c) * T_;
    #pragma unroll
    for (int m = 0; m < 6; ++m) XS[base + tq + 4*m] = f2bfb(a[m]);
  }
}

// ---------------------------------------------------------------------------
// k_final: per half (8 b's). Y1h/Y2h are [n][12288] with local col index.
// ---------------------------------------------------------------------------
__global__ __launch_bounds__(256) void k_final(
    const float* __restrict__ x,
    const ushort_t* __restrict__ XS, const ushort_t* __restrict__ Y1h,
    const ushort_t* __restrict__ Y2h,
    const float* __restrict__ W1T, const float* __restrict__ b_1,
    const float* __restrict__ WgT, const float* __restrict__ b_g,
    int h, float* __restrict__ out)
{
  const int n = blockIdx.x, bb = blockIdx.y, tid = threadIdx.x;
  const int b = h * 8 + bb;
  __shared__ float XSs[COUT_*T_], Y1s[COUT_*T_], Y2s[COUT_*T_];
  __shared__ float x1s[COUT_*T_], xts[CIN_*T_];
  size_t baseg = (size_t)n * XS_COLS + (size_t)b * COUT_ * T_;
  size_t baseh = (size_t)n * HALF_COLS + (size_t)bb * COUT_ * T_;
  for (int i = tid; i < COUT_*T_; i += 256) {
    XSs[i] = bfb2f(XS[baseg + i]);
    Y1s[i] = bfb2f(Y1h[baseh + i]);
    Y2s[i] = bfb2f(Y2h[baseh + i]);
  }
  for (int i = tid; i < CIN_*T_; i += 256) {
    int ci = i / T_, t = i % T_;
    xts[i] = x[(((size_t)b * CIN_ + ci) * N_ + n) * T_ + t];
  }
  __syncthreads();
  const int c = tid >> 2, tq = tid & 3;
  {
    float a[6];
    #pragma unroll
    for (int m = 0; m < 6; ++m) a[m] = b_1[c];
    for (int i = 0; i < CIN_; ++i) {
      float w = W1T[i*64+c];
      #pragma unroll
      for (int m = 0; m < 6; ++m) a[m] += w * xts[i*T_ + tq + 4*m];
    }
    #pragma unroll
    for (int m = 0; m < 6; ++m) x1s[c*T_ + tq + 4*m] = a[m];
  }
  __syncthreads();
  {
    float af[6], ag[6];
    #pragma unroll
    for (int m = 0; m < 6; ++m) { af[m] = b_g[c]; ag[m] = b_g[COUT_ + c]; }
    for (int j = 0; j < COUT_; ++j) {
      float wf0 = WgT[(3*j+0)*128 + c],      wf1 = WgT[(3*j+1)*128 + c],      wf2 = WgT[(3*j+2)*128 + c];
      float wg0 = WgT[(3*j+0)*128 + 64 + c], wg1 = WgT[(3*j+1)*128 + 64 + c], wg2 = WgT[(3*j+2)*128 + 64 + c];
      #pragma unroll
      for (int m = 0; m < 6; ++m) {
        int t = tq + 4*m;
        float xs = XSs[j*T_ + t], y1 = Y1s[j*T_ + t], y2 = Y2s[j*T_ + t];
        af[m] += wf0 * xs + wf1 * y1 + wf2 * y2;
        ag[m] += wg0 * xs + wg1 * y1 + wg2 * y2;
      }
    }
    #pragma unroll
    for (int m = 0; m < 6; ++m) {
      int t = tq + 4*m;
      float g = sigm_(ag[m]);
      out[(((size_t)b * COUT_ + c) * N_ + n) * T_ + t] = (af[m] + x1s[c*T_ + t]) * g;
    }
  }
}

// ---------------------------------------------------------------------------
extern "C" void kernel_launch(void* const* d_in, const int* in_sizes, int n_in,
                              void* d_out, int out_size, void* d_ws, size_t ws_size,
                              hipStream_t stream) {
  const float* x        = (const float*)d_in[0];
  const float* supports = (const float*)d_in[1];
  const float* CD       = (const float*)d_in[2];
  const float* CS       = (const float*)d_in[3];
  const float* adj      = (const float*)d_in[4];
  const float* W_de  = (const float*)d_in[5];  const float* b_de  = (const float*)d_in[6];
  const float* Wd    = (const float*)d_in[7];
  const float* W_pro = (const float*)d_in[8];  const float* b_pro = (const float*)d_in[9];
  const float* W_mii = (const float*)d_in[10]; const float* b_mii = (const float*)d_in[11];
  const float* W_1   = (const float*)d_in[12]; const float* b_1   = (const float*)d_in[13];
  const float* Wq_t  = (const float*)d_in[14]; const float* bq_t  = (const float*)d_in[15];
  const float* Wk_t  = (const float*)d_in[16]; const float* bk_t  = (const float*)d_in[17];
  const float* Wv_t  = (const float*)d_in[18]; const float* bv_t  = (const float*)d_in[19];
  const float* W_c1  = (const float*)d_in[20]; const float* b_c1  = (const float*)d_in[21];
  const float* Wq_s  = (const float*)d_in[22]; const float* bq_s  = (const float*)d_in[23];
  const float* Wk_s  = (const float*)d_in[24]; const float* bk_s  = (const float*)d_in[25];
  const float* Wv_s  = (const float*)d_in[26]; const float* bv_s  = (const float*)d_in[27];
  const float* W_g   = (const float*)d_in[28]; const float* b_g   = (const float*)d_in[29];
  float* out = (float*)d_out;

  char* ws = (char*)d_ws;
  float*    delay = (float*)(ws + OFF_DELAY);
  float*    Mbuf  = (float*)(ws + OFF_M);
  float*    Rbuf  = (float*)(ws + OFF_R);
  float*    u     = (float*)(ws + OFF_U);
  float*    WdeT  = (float*)(ws + OFF_WDET);
  float*    WqtT  = (float*)(ws + OFF_WQTT);
  float*    W1T   = (float*)(ws + OFF_W1T);
  float*    WmiiT = (float*)(ws + OFF_WMIIT);
  float*    WktT  = (float*)(ws + OFF_WKTT);
  float*    WvtT  = (float*)(ws + OFF_WVTT);
  float*    WqsT  = (float*)(ws + OFF_WQST);
  float*    WksT  = (float*)(ws + OFF_WKST);
  float*    WvsT  = (float*)(ws + OFF_WVST);
  float*    Wc1T  = (float*)(ws + OFF_WC1T);
  float*    WgT   = (float*)(ws + OFF_WGT);
  ushort_t* Sbf   = (ushort_t*)(ws + OFF_SBF);
  ushort_t* adjbf = (ushort_t*)(ws + OFF_ADJBF);
  ushort_t* STbf  = (ushort_t*)(ws + OFF_STBF);
  ushort_t* L2bf  = (ushort_t*)(ws + OFF_L2BF);
  ushort_t* Ue    = (ushort_t*)(ws + OFF_X1);
  ushort_t* P     = (ushort_t*)(ws + OFF_X1);   // overwrites Ue (dead)
  ushort_t* UeT   = (ushort_t*)(ws + OFF_X2);
  ushort_t* XST   = (ushort_t*)(ws + OFF_X2);   // overwrites UeT (dead)
  ushort_t* XS    = (ushort_t*)(ws + OFF_XS);
  ushort_t* Y1h   = (ushort_t*)(ws + OFF_Y1H);
  ushort_t* Y2h   = (ushort_t*)(ws + OFF_Y2H);

  (void)in_sizes; (void)n_in; (void)out_size; (void)ws_size;

  // 1) conversions + weight transposes
  k_prep<<<dim3((PREP_TOTAL + 255)/256), 256, 0, stream>>>(
      supports, adj, W_de, Wq_t, W_1, W_mii, Wk_t, Wv_t, Wq_s, Wk_s, Wv_s,
      W_c1, W_g, Sbf, adjbf, STbf,
      WdeT, WqtT, W1T, WmiiT, WktT, WvtT, WqsT, WksT, WvsT, Wc1T, WgT);
  // 2) delay / Mbuf / Rbuf
  k_pre<<<dim3((NT_ + N_*COUT_ + N_ + 255)/256), 256, 0, stream>>>(
      CD, Wd, CS, W_mii, adj, delay, Mbuf, Rbuf);
  // 3) L2 = 2*S@S - I  (bf16)
  k_mmx<2><<<dim3(8, 8), 256, 0, stream>>>(Sbf, STbf, L2bf, 1024);
  // 4) u + Ue
  k_u<<<dim3((BNT_ + 255)/256), 256, 0, stream>>>(x, W_pro, b_pro, CS, u, Ue);
  // 5) UeT = Ue^T
  k_tr<<<dim3(UE_COLS/32, N_/32), 256, 0, stream>>>(Ue, UeT, N_, UE_COLS);
  // 6) P = adj @ Ue
  k_mmx<0><<<dim3(UE_COLS/128, N_/128), 256, 0, stream>>>(adjbf, UeT, P, UE_COLS);
  // 7) fused attention pipeline -> XS
  k_attn<<<dim3(N_, B_), 256, 0, stream>>>(
      x, delay, Mbuf, Rbuf, u, P,
      WdeT, b_de, WmiiT, b_mii, W1T, b_1,
      WqtT, bq_t, WktT, bk_t, WvtT, bv_t,
      Wc1T, b_c1, WqsT, bq_s, WksT, bk_s, WvsT, bv_s, XS);
  // 8) per half: transpose, Y1 = S@XS, Y2 = L2@XS, final
  for (int h = 0; h < 2; ++h) {
    k_tr<<<dim3(HALF_COLS/32, N_/32), 256, 0, stream>>>(
        XS + (size_t)h * HALF_COLS, XST, N_, XS_COLS);
    k_mmx<0><<<dim3(HALF_COLS/128, N_/128), 256, 0, stream>>>(Sbf, XST, Y1h, HALF_COLS);
    k_mmx<0><<<dim3(HALF_COLS/128, N_/128), 256, 0, stream>>>(L2bf, XST, Y2h, HALF_COLS);
    k_final<<<dim3(N_, 8), 256, 0, stream>>>(
        x, XS, Y1h, Y2h, W1T, b_1, WgT, b_g, h, out);
  }
}

// Round 3
// 1141.073 us; speedup vs baseline: 2.7590x; 1.6230x over previous
//
#include <hip/hip_runtime.h>
#include <cstdint>
#include <cstddef>

#define B_    16
#define CIN_  32
#define COUT_ 64
#define N_    1024
#define T_    24
#define SD_   16
#define DD_   16

#define NT_      (N_*T_)          // 24576
#define BNT_     (B_*N_*T_)       // 393216
#define UE_COLS  (B_*T_*SD_)      // 6144
#define XS_COLS  (B_*COUT_*T_)    // 24576
#define HALF_COLS (XS_COLS/2)     // 12288

typedef unsigned short ushort_t;
using bf16x8 = __attribute__((ext_vector_type(8))) short;
using f32x4  = __attribute__((ext_vector_type(4))) float;

// ---- workspace byte offsets ----
#define OFF_DELAY 0ul
#define OFF_M     98304ul
#define OFF_R     360448ul
#define OFF_U     364544ul
#define OFF_WDET  1937408ul
#define OFF_WQTT  1945600ul
#define OFF_W1T   1953792ul
#define OFF_WMIIT 1961984ul
#define OFF_WKTT  1966080ul
#define OFF_WVTT  1982464ul
#define OFF_WQST  1998848ul
#define OFF_WKST  2015232ul
#define OFF_WVST  2031616ul
#define OFF_WC1T  2048000ul
#define OFF_WGT   2097152ul
#define OFF_SBF   2195456ul
#define OFF_ADJBF 4292608ul
#define OFF_STBF  6389760ul
#define OFF_L2BF  8486912ul
#define OFF_X1    10584064ul             // Ue then P (bf16 1024*6144)
#define OFF_X2    23166976ul             // UeT then XST_h
#define OFF_XS    48332800ul             // bf16 1024*24576
#define OFF_Y1H   98664448ul             // bf16 1024*12288
#define OFF_Y2H   123830272ul            // bf16 1024*12288
#define OFF_WBF   148996096ul            // bf16 weights, 40960 elems = 81920 B

// bf16 weight sub-offsets (element index within WBF)
#define WB_DE   0
#define WB_QT   2048
#define WB_1    4096
#define WB_MIIA 6144
#define WB_KT   8192
#define WB_VT   12288
#define WB_QS   16384
#define WB_KS   20480
#define WB_VS   24576
#define WB_C1A  28672   // [3][64][64]
#define WB_TOTAL 40960

__device__ __forceinline__ float bfb2f(ushort_t h) {
  union { unsigned u; float f; } v; v.u = ((unsigned)h) << 16; return v.f;
}
__device__ __forceinline__ ushort_t f2bfb(float f) {
  union { float f; unsigned u; } v; v.f = f;
  unsigned u = v.u;
  return (ushort_t)((u + 0x7fffu + ((u >> 16) & 1u)) >> 16);
}
__device__ __forceinline__ float sigm_(float z) { return 1.f / (1.f + expf(-z)); }

__device__ __forceinline__ void gl_lds16(const ushort_t* g, ushort_t* l) {
  __builtin_amdgcn_global_load_lds(
      (const __attribute__((address_space(1))) unsigned int*)g,
      (__attribute__((address_space(3))) unsigned int*)l, 16, 0, 0);
}

__device__ __forceinline__ void st4bf(ushort_t* p, float v0, float v1, float v2, float v3) {
  uint2 w;
  w.x = (unsigned)f2bfb(v0) | ((unsigned)f2bfb(v1) << 16);
  w.y = (unsigned)f2bfb(v2) | ((unsigned)f2bfb(v3) << 16);
  *(uint2*)p = w;
}

// ---------------------------------------------------------------------------
// k_prep: bf16 supports/adj/S^T, f32 transposed W1/Wg (k_final), bf16 row-major
// weight copies for the MFMA attention kernel.
// ---------------------------------------------------------------------------
__global__ __launch_bounds__(256) void k_prep(
    const float* __restrict__ supports, const float* __restrict__ adj,
    const float* __restrict__ W_de, const float* __restrict__ Wq_t,
    const float* __restrict__ W_1, const float* __restrict__ W_mii,
    const float* __restrict__ Wk_t, const float* __restrict__ Wv_t,
    const float* __restrict__ Wq_s, const float* __restrict__ Wk_s,
    const float* __restrict__ Wv_s, const float* __restrict__ W_c1,
    const float* __restrict__ W_g,
    ushort_t* __restrict__ Sbf, ushort_t* __restrict__ adjbf,
    ushort_t* __restrict__ STbf,
    float* __restrict__ W1T, float* __restrict__ WgT,
    ushort_t* __restrict__ WBF)
{
  int idx = blockIdx.x * 256 + threadIdx.x;
  if (idx < N_*N_) {
    Sbf[idx]   = f2bfb(supports[idx]);
    adjbf[idx] = f2bfb(adj[idx]);
    int n = idx >> 10, k = idx & 1023;
    STbf[idx]  = f2bfb(supports[k*N_ + n]);
  }
  int j = idx - N_*N_;
  if (j < 0) return;
  if (j < 2048) { int k = j>>6, c = j&63; W1T[j] = W_1[c*32 + k]; return; }
  j -= 2048;
  if (j < 24576) { int g = j>>7, cc = j&127; WgT[j] = W_g[cc*192 + g]; return; }
  j -= 24576;
  // bf16 row-major weight copies
  if (j < 2048) { WBF[WB_DE + j] = f2bfb(W_de[j]); return; }
  j -= 2048;
  if (j < 2048) { WBF[WB_QT + j] = f2bfb(Wq_t[j]); return; }
  j -= 2048;
  if (j < 2048) { WBF[WB_1 + j] = f2bfb(W_1[j]); return; }
  j -= 2048;
  if (j < 2048) { int c = j>>5, k = j&31;
                  WBF[WB_MIIA + j] = (k < 16) ? f2bfb(W_mii[c*16 + k]) : (ushort_t)0; return; }
  j -= 2048;
  if (j < 4096) { WBF[WB_KT + j] = f2bfb(Wk_t[j]); return; }
  j -= 4096;
  if (j < 4096) { WBF[WB_VT + j] = f2bfb(Wv_t[j]); return; }
  j -= 4096;
  if (j < 4096) { WBF[WB_QS + j] = f2bfb(Wq_s[j]); return; }
  j -= 4096;
  if (j < 4096) { WBF[WB_KS + j] = f2bfb(Wk_s[j]); return; }
  j -= 4096;
  if (j < 4096) { WBF[WB_VS + j] = f2bfb(Wv_s[j]); return; }
  j -= 4096;
  if (j < 12288) { int d = j >> 12, r = j & 4095, c = r >> 6, jj = r & 63;
                   WBF[WB_C1A + j] = f2bfb(W_c1[(c*64 + jj)*3 + d]); return; }
}
#define PREP_TOTAL (N_*N_ + 2048 + 24576 + WB_TOTAL)

// ---------------------------------------------------------------------------
// k_pre: delay, Mbuf, Rbuf
// ---------------------------------------------------------------------------
__global__ __launch_bounds__(256) void k_pre(
    const float* __restrict__ CD, const float* __restrict__ Wd,
    const float* __restrict__ CS, const float* __restrict__ W_mii,
    const float* __restrict__ adj,
    float* __restrict__ delay, float* __restrict__ Mbuf, float* __restrict__ Rbuf)
{
  int idx = blockIdx.x * 256 + threadIdx.x;
  if (idx < NT_) {
    int n = idx / T_, t = idx % T_;
    float z = 0.f;
    #pragma unroll
    for (int d = 0; d < DD_; ++d) z += CD[n*DD_ + d] * Wd[d*T_ + t];
    delay[idx] = sigm_(tanhf(z));
  }
  int i2 = idx - NT_;
  if (i2 >= 0 && i2 < N_*COUT_) {
    int n = i2 / COUT_, c = i2 % COUT_;
    float z = 0.f;
    #pragma unroll
    for (int e = 0; e < SD_; ++e) z += CS[n*SD_ + e] * W_mii[c*SD_ + e];
    Mbuf[i2] = z;
  }
  int i3 = idx - NT_ - N_*COUT_;
  if (i3 >= 0 && i3 < N_) {
    const float* row = adj + (size_t)i3 * N_;
    float s = 0.f;
    for (int m = 0; m < N_; ++m) s += row[m];
    Rbuf[i3] = s;
  }
}

// ---------------------------------------------------------------------------
// k_u: u + Ue
// ---------------------------------------------------------------------------
__global__ __launch_bounds__(256) void k_u(
    const float* __restrict__ x, const float* __restrict__ W_pro,
    const float* __restrict__ b_pro, const float* __restrict__ CS,
    float* __restrict__ u, ushort_t* __restrict__ Ue)
{
  int idx = blockIdx.x * 256 + threadIdx.x;
  if (idx >= BNT_) return;
  int t = idx % T_;
  int n = (idx / T_) % N_;
  int b = idx / (T_ * N_);
  const float* xp = x + ((size_t)b * CIN_ * N_ + n) * T_ + t;
  float z = b_pro[0];
  #pragma unroll
  for (int i = 0; i < CIN_; ++i) z += W_pro[i] * xp[(size_t)i * NT_];
  u[idx] = z;
  ushort_t* up = Ue + (size_t)n * UE_COLS + (b * T_ + t) * SD_;
  #pragma unroll
  for (int e = 0; e < SD_; ++e) up[e] = f2bfb(z * CS[n*SD_ + e]);
}

// ---------------------------------------------------------------------------
// k_tr: bf16 transpose dst[c*R + r] = src[r*sstride + c]
// ---------------------------------------------------------------------------
__global__ __launch_bounds__(256) void k_tr(
    const ushort_t* __restrict__ src, ushort_t* __restrict__ dst,
    int R, int sstride)
{
  __shared__ ushort_t tb[32][33];
  const int tid = threadIdx.x;
  const int tx = tid & 31, ty = tid >> 5;
  const int c0 = blockIdx.x * 32, r0 = blockIdx.y * 32;
  #pragma unroll
  for (int p = 0; p < 4; ++p) {
    int r = r0 + ty + p*8;
    tb[ty + p*8][tx] = src[(size_t)r * sstride + c0 + tx];
  }
  __syncthreads();
  #pragma unroll
  for (int p = 0; p < 4; ++p) {
    int c = c0 + ty + p*8;
    dst[(size_t)c * R + r0 + tx] = tb[tx][ty + p*8];
  }
}

// ---------------------------------------------------------------------------
// k_mmx: MFMA GEMM (unchanged from R2, passed)
// ---------------------------------------------------------------------------
template<int MODE>
__global__ __launch_bounds__(256) void k_mmx(
    const ushort_t* __restrict__ Abf, const ushort_t* __restrict__ BT,
    ushort_t* __restrict__ Cc, int ncols)
{
  __shared__ ushort_t As[128*64];
  __shared__ ushort_t Bs[128*64];
  const int tid  = threadIdx.x;
  const int wave = tid >> 6, lane = tid & 63;
  const int row0 = blockIdx.y * 128;
  const int col0 = blockIdx.x * 128;
  const int wm = (wave >> 1) * 64, wn = (wave & 1) * 64;
  const int l15 = lane & 15, quad = lane >> 4, l7 = lane & 7;

  f32x4 acc[4][4];
  #pragma unroll
  for (int i = 0; i < 4; ++i)
    #pragma unroll
    for (int j = 0; j < 4; ++j) acc[i][j] = (f32x4){0.f,0.f,0.f,0.f};

  for (int kb = 0; kb < 1024; kb += 64) {
    #pragma unroll
    for (int p = 0; p < 4; ++p) {
      int chunk = p*256 + tid;
      int r = chunk >> 3, pc = chunk & 7;
      int kc = pc ^ (r & 7);
      gl_lds16(Abf + (size_t)(row0 + r)*1024 + (kb + kc*8), &As[chunk*8]);
    }
    #pragma unroll
    for (int p = 0; p < 4; ++p) {
      int chunk = p*256 + tid;
      int r = chunk >> 3, pc = chunk & 7;
      int kc = pc ^ (r & 7);
      gl_lds16(BT + (size_t)(col0 + r)*1024 + (kb + kc*8), &Bs[chunk*8]);
    }
    __syncthreads();
    #pragma unroll
    for (int kh = 0; kh < 2; ++kh) {
      const int kcb = kh * 4;
      bf16x8 af[4], bfr[4];
      #pragma unroll
      for (int mi = 0; mi < 4; ++mi)
        af[mi] = *(const bf16x8*)&As[(wm + mi*16 + l15)*64 + (((kcb + quad) ^ l7) << 3)];
      #pragma unroll
      for (int ni = 0; ni < 4; ++ni)
        bfr[ni] = *(const bf16x8*)&Bs[(wn + ni*16 + l15)*64 + (((kcb + quad) ^ l7) << 3)];
      #pragma unroll
      for (int mi = 0; mi < 4; ++mi)
        #pragma unroll
        for (int ni = 0; ni < 4; ++ni)
          acc[mi][ni] = __builtin_amdgcn_mfma_f32_16x16x32_bf16(
              af[mi], bfr[ni], acc[mi][ni], 0, 0, 0);
    }
    __syncthreads();
  }

  #pragma unroll
  for (int mi = 0; mi < 4; ++mi) {
    int grow_b = row0 + wm + mi*16 + quad*4;
    #pragma unroll
    for (int ni = 0; ni < 4; ++ni) {
      int gcol = col0 + wn + ni*16 + l15;
      #pragma unroll
      for (int j = 0; j < 4; ++j) {
        float v = acc[mi][ni][j];
        int grow = grow_b + j;
        if (MODE == 2) v = 2.f*v - ((grow == gcol) ? 1.f : 0.f);
        Cc[(size_t)grow * ncols + gcol] = f2bfb(v);
      }
    }
  }
}

// ---------------------------------------------------------------------------
// k_attn_mfma: one block per (n,b). Full attention pipeline on MFMA.
// All intermediates bf16 in LDS, layout X[t][c] (c contiguous, stride 72).
// ---------------------------------------------------------------------------
#define SW 72
__global__ __launch_bounds__(256) void k_attn_mfma(
    const float* __restrict__ x,
    const float* __restrict__ delay, const float* __restrict__ Mbuf,
    const float* __restrict__ Rbuf, const float* __restrict__ u,
    const ushort_t* __restrict__ P,
    const ushort_t* __restrict__ WBF,
    const float* __restrict__ b_de, const float* __restrict__ bq_t,
    const float* __restrict__ b_1,  const float* __restrict__ b_mii,
    const float* __restrict__ bk_t, const float* __restrict__ bv_t,
    const float* __restrict__ bq_s, const float* __restrict__ bk_s,
    const float* __restrict__ bv_s, const float* __restrict__ b_c1,
    ushort_t* __restrict__ XS)
{
  const int n = blockIdx.x, b = blockIdx.y;
  const int tid = threadIdx.x, wave = tid >> 6, lane = tid & 63;
  const int l15 = lane & 15, quad = lane >> 4;

  __shared__ ushort_t Bc[32*SW];     // x^T  [t][i], cols 0..31
  __shared__ ushort_t Pts[32*40];    // P^T  [t][e], cols 16..31 zero
  __shared__ ushort_t bufD[32*SW];   // D, later x1c
  __shared__ ushort_t bufQ[32*SW];   // Q_t, later Q_s
  __shared__ ushort_t bufK[32*SW];   // K_t, later K_s
  __shared__ ushort_t x1s[32*SW];    // x_input1
  __shared__ ushort_t Sts[32*SW];    // S
  __shared__ ushort_t XDg[34*SW];    // XD with zero guard rows (row = 1+t)
  __shared__ ushort_t V2[64*40];     // V [c][s], cols 24..31 zero
  __shared__ float    scf[24*25];
  __shared__ ushort_t scb[32*40];    // softmax(A) [t][s], cols 24..31 zero
  __shared__ float    delay_s[32], urow[32], Mrow[64];

  // ---- staging ----
  for (int i = tid; i < 768; i += 256) {
    int ci = i / 24, t = i - ci*24;
    Bc[t*SW + ci] = f2bfb(x[(((size_t)b*CIN_ + ci)*N_ + n)*T_ + t]);
  }
  for (int i = tid; i < 768; i += 256) {
    int t = i >> 5, e = i & 31;
    Pts[t*40 + e] = (e < 16) ? P[(size_t)n*UE_COLS + (b*T_ + t)*SD_ + e] : (ushort_t)0;
  }
  if (tid < 32)       urow[tid] = (tid < 24) ? u[((size_t)b*N_ + n)*T_ + tid] : 0.f;
  else if (tid < 64)  { int t = tid - 32; delay_s[t] = (t < 24) ? delay[n*T_ + t] : 0.f; }
  else if (tid < 128) Mrow[tid - 64] = Mbuf[n*COUT_ + (tid - 64)];
  for (int i = tid; i < 64*40; i += 256) V2[i] = 0;
  for (int i = tid; i < 34*SW; i += 256) XDg[i] = 0;
  __syncthreads();

  const int c0 = wave * 16;
  const float Rn = Rbuf[n];

  // ---- phase 2: D, Q_t, x_input1 (K=32 from Bc), S (K=32 from Pts) ----
  {
    bf16x8 aD = *(const bf16x8*)(WBF + WB_DE   + (c0+l15)*32 + quad*8);
    bf16x8 aQ = *(const bf16x8*)(WBF + WB_QT   + (c0+l15)*32 + quad*8);
    bf16x8 a1 = *(const bf16x8*)(WBF + WB_1    + (c0+l15)*32 + quad*8);
    bf16x8 aS = *(const bf16x8*)(WBF + WB_MIIA + (c0+l15)*32 + quad*8);
    float4 bD4 = *(const float4*)&b_de [c0 + quad*4];
    float4 bQ4 = *(const float4*)&bq_t [c0 + quad*4];
    float4 b14 = *(const float4*)&b_1  [c0 + quad*4];
    float4 bS4 = *(const float4*)&b_mii[c0 + quad*4];
    float4 Mv4 = *(const float4*)&Mrow [c0 + quad*4];
    float bD[4] = {bD4.x,bD4.y,bD4.z,bD4.w};
    float bQ[4] = {bQ4.x,bQ4.y,bQ4.z,bQ4.w};
    float b1a[4] = {b14.x,b14.y,b14.z,b14.w};
    float bS[4] = {bS4.x,bS4.y,bS4.z,bS4.w};
    float Mv[4] = {Mv4.x,Mv4.y,Mv4.z,Mv4.w};
    #pragma unroll
    for (int nt = 0; nt < 2; ++nt) {
      int bt = nt*16 + l15;
      bf16x8 bx = *(const bf16x8*)&Bc[bt*SW + quad*8];
      bf16x8 bp = *(const bf16x8*)&Pts[bt*40 + quad*8];
      f32x4 z = {0.f,0.f,0.f,0.f};
      f32x4 accD = __builtin_amdgcn_mfma_f32_16x16x32_bf16(aD, bx, z, 0,0,0);
      f32x4 accQ = __builtin_amdgcn_mfma_f32_16x16x32_bf16(aQ, bx, z, 0,0,0);
      f32x4 acc1 = __builtin_amdgcn_mfma_f32_16x16x32_bf16(a1, bx, z, 0,0,0);
      f32x4 accS = __builtin_amdgcn_mfma_f32_16x16x32_bf16(aS, bp, z, 0,0,0);
      float dl = delay_s[bt], ut = urow[bt];
      st4bf(&bufD[bt*SW + c0 + quad*4],
            (accD[0]+bD[0])*dl, (accD[1]+bD[1])*dl, (accD[2]+bD[2])*dl, (accD[3]+bD[3])*dl);
      st4bf(&bufQ[bt*SW + c0 + quad*4],
            accQ[0]+bQ[0], accQ[1]+bQ[1], accQ[2]+bQ[2], accQ[3]+bQ[3]);
      st4bf(&x1s[bt*SW + c0 + quad*4],
            acc1[0]+b1a[0], acc1[1]+b1a[1], acc1[2]+b1a[2], acc1[3]+b1a[3]);
      st4bf(&Sts[bt*SW + c0 + quad*4],
            accS[0] + ut*Mv[0] + bS[0]*(1.f+Rn), accS[1] + ut*Mv[1] + bS[1]*(1.f+Rn),
            accS[2] + ut*Mv[2] + bS[2]*(1.f+Rn), accS[3] + ut*Mv[3] + bS[3]*(1.f+Rn));
    }
  }
  __syncthreads();

  // ---- phase 3: K_t, V_t from D (K=64) ----
  {
    bf16x8 aK0 = *(const bf16x8*)(WBF + WB_KT + (c0+l15)*64 + quad*8);
    bf16x8 aK1 = *(const bf16x8*)(WBF + WB_KT + (c0+l15)*64 + 32 + quad*8);
    bf16x8 aV0 = *(const bf16x8*)(WBF + WB_VT + (c0+l15)*64 + quad*8);
    bf16x8 aV1 = *(const bf16x8*)(WBF + WB_VT + (c0+l15)*64 + 32 + quad*8);
    float4 bK4 = *(const float4*)&bk_t[c0 + quad*4];
    float4 bV4 = *(const float4*)&bv_t[c0 + quad*4];
    float bK[4] = {bK4.x,bK4.y,bK4.z,bK4.w};
    float bV[4] = {bV4.x,bV4.y,bV4.z,bV4.w};
    #pragma unroll
    for (int nt = 0; nt < 2; ++nt) {
      int bt = nt*16 + l15;
      bf16x8 b0 = *(const bf16x8*)&bufD[bt*SW + quad*8];
      bf16x8 b1v = *(const bf16x8*)&bufD[bt*SW + 32 + quad*8];
      f32x4 accK = {0.f,0.f,0.f,0.f}, accV = {0.f,0.f,0.f,0.f};
      accK = __builtin_amdgcn_mfma_f32_16x16x32_bf16(aK0, b0,  accK, 0,0,0);
      accK = __builtin_amdgcn_mfma_f32_16x16x32_bf16(aK1, b1v, accK, 0,0,0);
      accV = __builtin_amdgcn_mfma_f32_16x16x32_bf16(aV0, b0,  accV, 0,0,0);
      accV = __builtin_amdgcn_mfma_f32_16x16x32_bf16(aV1, b1v, accV, 0,0,0);
      st4bf(&bufK[bt*SW + c0 + quad*4],
            accK[0]+bK[0], accK[1]+bK[1], accK[2]+bK[2], accK[3]+bK[3]);
      if (bt < 24) {
        #pragma unroll
        for (int r = 0; r < 4; ++r)
          V2[(c0 + quad*4 + r)*40 + bt] = f2bfb(accV[r] + bV[r]);
      }
    }
  }
  __syncthreads();

  // ---- phase 4: scores_t = 0.125 * Q^T K ----
  {
    int mt = (wave >> 1) * 16, ns = (wave & 1) * 16;
    bf16x8 a0 = *(const bf16x8*)&bufQ[(mt+l15)*SW + quad*8];
    bf16x8 a1f = *(const bf16x8*)&bufQ[(mt+l15)*SW + 32 + quad*8];
    bf16x8 b0 = *(const bf16x8*)&bufK[(ns+l15)*SW + quad*8];
    bf16x8 b1f = *(const bf16x8*)&bufK[(ns+l15)*SW + 32 + quad*8];
    f32x4 acc = {0.f,0.f,0.f,0.f};
    acc = __builtin_amdgcn_mfma_f32_16x16x32_bf16(a0, b0, acc, 0,0,0);
    acc = __builtin_amdgcn_mfma_f32_16x16x32_bf16(a1f, b1f, acc, 0,0,0);
    int s = ns + l15;
    if (s < 24) {
      #pragma unroll
      for (int r = 0; r < 4; ++r) {
        int t = mt + quad*4 + r;
        if (t < 24) scf[t*25 + s] = 0.125f * acc[r];
      }
    }
  }
  __syncthreads();

  // ---- softmax 1 ----
  if (tid < 24) {
    float mx = -1e30f;
    for (int s2 = 0; s2 < 24; ++s2) mx = fmaxf(mx, scf[tid*25 + s2]);
    float sm = 0.f;
    for (int s2 = 0; s2 < 24; ++s2) { float e = expf(scf[tid*25 + s2] - mx); scf[tid*25 + s2] = e; sm += e; }
    float inv = 1.f / sm;
    for (int s2 = 0; s2 < 24; ++s2) scb[tid*40 + s2] = f2bfb(scf[tid*25 + s2] * inv);
    for (int s2 = 24; s2 < 32; ++s2) scb[tid*40 + s2] = 0;
  }
  __syncthreads();

  // ---- phase 5: XD^T[t][c] = A @ V^T + x1 -> XDg (guard layout) ----
  {
    int nc = wave * 16;
    bf16x8 bv0 = *(const bf16x8*)&V2[(nc + l15)*40 + quad*8];
    #pragma unroll
    for (int mt = 0; mt < 2; ++mt) {
      bf16x8 af = *(const bf16x8*)&scb[(mt*16 + l15)*40 + quad*8];
      f32x4 acc = {0.f,0.f,0.f,0.f};
      acc = __builtin_amdgcn_mfma_f32_16x16x32_bf16(af, bv0, acc, 0,0,0);
      int ccol = nc + l15;
      #pragma unroll
      for (int r = 0; r < 4; ++r) {
        int t = mt*16 + quad*4 + r;
        if (t < 24)
          XDg[(1 + t)*SW + ccol] = f2bfb(acc[r] + bfb2f(x1s[t*SW + ccol]));
      }
    }
  }
  __syncthreads();

  // ---- phase 6: x1 = conv_t(XD) -> bufD ----
  {
    float4 bc4 = *(const float4*)&b_c1[c0 + quad*4];
    float bc[4] = {bc4.x,bc4.y,bc4.z,bc4.w};
    f32x4 acc0 = {0.f,0.f,0.f,0.f}, acc1v = {0.f,0.f,0.f,0.f};
    #pragma unroll
    for (int d = 0; d < 3; ++d) {
      const ushort_t* Ad = WBF + WB_C1A + d*4096;
      bf16x8 a0 = *(const bf16x8*)(Ad + (c0+l15)*64 + quad*8);
      bf16x8 a1f = *(const bf16x8*)(Ad + (c0+l15)*64 + 32 + quad*8);
      {
        int rr = 0*16 + l15 + d;
        bf16x8 b0 = *(const bf16x8*)&XDg[rr*SW + quad*8];
        bf16x8 b1f = *(const bf16x8*)&XDg[rr*SW + 32 + quad*8];
        acc0 = __builtin_amdgcn_mfma_f32_16x16x32_bf16(a0, b0, acc0, 0,0,0);
        acc0 = __builtin_amdgcn_mfma_f32_16x16x32_bf16(a1f, b1f, acc0, 0,0,0);
      }
      {
        int rr = 1*16 + l15 + d;
        bf16x8 b0 = *(const bf16x8*)&XDg[rr*SW + quad*8];
        bf16x8 b1f = *(const bf16x8*)&XDg[rr*SW + 32 + quad*8];
        acc1v = __builtin_amdgcn_mfma_f32_16x16x32_bf16(a0, b0, acc1v, 0,0,0);
        acc1v = __builtin_amdgcn_mfma_f32_16x16x32_bf16(a1f, b1f, acc1v, 0,0,0);
      }
    }
    st4bf(&bufD[(0*16 + l15)*SW + c0 + quad*4],
          acc0[0]+bc[0], acc0[1]+bc[1], acc0[2]+bc[2], acc0[3]+bc[3]);
    st4bf(&bufD[(1*16 + l15)*SW + c0 + quad*4],
          acc1v[0]+bc[0], acc1v[1]+bc[1], acc1v[2]+bc[2], acc1v[3]+bc[3]);
  }
  __syncthreads();

  // ---- phase 7: Q_s (from x1=bufD), K_s, V_s (from S) ----
  {
    bf16x8 aq0 = *(const bf16x8*)(WBF + WB_QS + (c0+l15)*64 + quad*8);
    bf16x8 aq1 = *(const bf16x8*)(WBF + WB_QS + (c0+l15)*64 + 32 + quad*8);
    bf16x8 ak0 = *(const bf16x8*)(WBF + WB_KS + (c0+l15)*64 + quad*8);
    bf16x8 ak1 = *(const bf16x8*)(WBF + WB_KS + (c0+l15)*64 + 32 + quad*8);
    bf16x8 av0 = *(const bf16x8*)(WBF + WB_VS + (c0+l15)*64 + quad*8);
    bf16x8 av1 = *(const bf16x8*)(WBF + WB_VS + (c0+l15)*64 + 32 + quad*8);
    float4 bq4 = *(const float4*)&bq_s[c0 + quad*4];
    float4 bk4 = *(const float4*)&bk_s[c0 + quad*4];
    float4 bv4 = *(const float4*)&bv_s[c0 + quad*4];
    float bq[4] = {bq4.x,bq4.y,bq4.z,bq4.w};
    float bk[4] = {bk4.x,bk4.y,bk4.z,bk4.w};
    float bv[4] = {bv4.x,bv4.y,bv4.z,bv4.w};
    #pragma unroll
    for (int nt = 0; nt < 2; ++nt) {
      int bt = nt*16 + l15;
      bf16x8 bx0 = *(const bf16x8*)&bufD[bt*SW + quad*8];
      bf16x8 bx1 = *(const bf16x8*)&bufD[bt*SW + 32 + quad*8];
      bf16x8 bs0 = *(const bf16x8*)&Sts[bt*SW + quad*8];
      bf16x8 bs1 = *(const bf16x8*)&Sts[bt*SW + 32 + quad*8];
      f32x4 accQ = {0.f,0.f,0.f,0.f}, accK = {0.f,0.f,0.f,0.f}, accV = {0.f,0.f,0.f,0.f};
      accQ = __builtin_amdgcn_mfma_f32_16x16x32_bf16(aq0, bx0, accQ, 0,0,0);
      accQ = __builtin_amdgcn_mfma_f32_16x16x32_bf16(aq1, bx1, accQ, 0,0,0);
      accK = __builtin_amdgcn_mfma_f32_16x16x32_bf16(ak0, bs0, accK, 0,0,0);
      accK = __builtin_amdgcn_mfma_f32_16x16x32_bf16(ak1, bs1, accK, 0,0,0);
      accV = __builtin_amdgcn_mfma_f32_16x16x32_bf16(av0, bs0, accV, 0,0,0);
      accV = __builtin_amdgcn_mfma_f32_16x16x32_bf16(av1, bs1, accV, 0,0,0);
      st4bf(&bufQ[bt*SW + c0 + quad*4],
            accQ[0]+bq[0], accQ[1]+bq[1], accQ[2]+bq[2], accQ[3]+bq[3]);
      st4bf(&bufK[bt*SW + c0 + quad*4],
            accK[0]+bk[0], accK[1]+bk[1], accK[2]+bk[2], accK[3]+bk[3]);
      if (bt < 24) {
        #pragma unroll
        for (int r = 0; r < 4; ++r)
          V2[(c0 + quad*4 + r)*40 + bt] = f2bfb(accV[r] + bv[r]);
      }
    }
  }
  __syncthreads();

  // ---- phase 8: scores_s ----
  {
    int mt = (wave >> 1) * 16, ns = (wave & 1) * 16;
    bf16x8 a0 = *(const bf16x8*)&bufQ[(mt+l15)*SW + quad*8];
    bf16x8 a1f = *(const bf16x8*)&bufQ[(mt+l15)*SW + 32 + quad*8];
    bf16x8 b0 = *(const bf16x8*)&bufK[(ns+l15)*SW + quad*8];
    bf16x8 b1f = *(const bf16x8*)&bufK[(ns+l15)*SW + 32 + quad*8];
    f32x4 acc = {0.f,0.f,0.f,0.f};
    acc = __builtin_amdgcn_mfma_f32_16x16x32_bf16(a0, b0, acc, 0,0,0);
    acc = __builtin_amdgcn_mfma_f32_16x16x32_bf16(a1f, b1f, acc, 0,0,0);
    int s = ns + l15;
    if (s < 24) {
      #pragma unroll
      for (int r = 0; r < 4; ++r) {
        int t = mt + quad*4 + r;
        if (t < 24) scf[t*25 + s] = 0.125f * acc[r];
      }
    }
  }
  __syncthreads();

  // ---- softmax 2 ----
  if (tid < 24) {
    float mx = -1e30f;
    for (int s2 = 0; s2 < 24; ++s2) mx = fmaxf(mx, scf[tid*25 + s2]);
    float sm = 0.f;
    for (int s2 = 0; s2 < 24; ++s2) { float e = expf(scf[tid*25 + s2] - mx); scf[tid*25 + s2] = e; sm += e; }
    float inv = 1.f / sm;
    for (int s2 = 0; s2 < 24; ++s2) scb[tid*40 + s2] = f2bfb(scf[tid*25 + s2] * inv);
    for (int s2 = 24; s2 < 32; ++s2) scb[tid*40 + s2] = 0;
  }
  __syncthreads();

  // ---- phase 9: XS = A_s @ V_s -> global [n][b][c][t] ----
  {
    int nc = wave * 16;
    bf16x8 bv0 = *(const bf16x8*)&V2[(nc + l15)*40 + quad*8];
    #pragma unroll
    for (int mt = 0; mt < 2; ++mt) {
      bf16x8 af = *(const bf16x8*)&scb[(mt*16 + l15)*40 + quad*8];
      f32x4 acc = {0.f,0.f,0.f,0.f};
      acc = __builtin_amdgcn_mfma_f32_16x16x32_bf16(af, bv0, acc, 0,0,0);
      int ccol = nc + l15;
      int t0 = mt*16 + quad*4;
      if (t0 < 24) {
        uint2 w;
        w.x = (unsigned)f2bfb(acc[0]) | ((unsigned)f2bfb(acc[1]) << 16);
        w.y = (unsigned)f2bfb(acc[2]) | ((unsigned)f2bfb(acc[3]) << 16);
        *(uint2*)(XS + (size_t)n*XS_COLS + (size_t)b*COUT_*T_ + ccol*T_ + t0) = w;
      }
    }
  }
}

// ---------------------------------------------------------------------------
// k_final: unchanged from R2
// ---------------------------------------------------------------------------
__global__ __launch_bounds__(256) void k_final(
    const float* __restrict__ x,
    const ushort_t* __restrict__ XS, const ushort_t* __restrict__ Y1h,
    const ushort_t* __restrict__ Y2h,
    const float* __restrict__ W1T, const float* __restrict__ b_1,
    const float* __restrict__ WgT, const float* __restrict__ b_g,
    int h, float* __restrict__ out)
{
  const int n = blockIdx.x, bb = blockIdx.y, tid = threadIdx.x;
  const int b = h * 8 + bb;
  __shared__ float XSs[COUT_*T_], Y1s[COUT_*T_], Y2s[COUT_*T_];
  __shared__ float x1sh[COUT_*T_], xts[CIN_*T_];
  size_t baseg = (size_t)n * XS_COLS + (size_t)b * COUT_ * T_;
  size_t baseh = (size_t)n * HALF_COLS + (size_t)bb * COUT_ * T_;
  for (int i = tid; i < COUT_*T_; i += 256) {
    XSs[i] = bfb2f(XS[baseg + i]);
    Y1s[i] = bfb2f(Y1h[baseh + i]);
    Y2s[i] = bfb2f(Y2h[baseh + i]);
  }
  for (int i = tid; i < CIN_*T_; i += 256) {
    int ci = i / T_, t = i % T_;
    xts[i] = x[(((size_t)b * CIN_ + ci) * N_ + n) * T_ + t];
  }
  __syncthreads();
  const int c = tid >> 2, tq = tid & 3;
  {
    float a[6];
    #pragma unroll
    for (int m = 0; m < 6; ++m) a[m] = b_1[c];
    for (int i = 0; i < CIN_; ++i) {
      float w = W1T[i*64+c];
      #pragma unroll
      for (int m = 0; m < 6; ++m) a[m] += w * xts[i*T_ + tq + 4*m];
    }
    #pragma unroll
    for (int m = 0; m < 6; ++m) x1sh[c*T_ + tq + 4*m] = a[m];
  }
  __syncthreads();
  {
    float af[6], ag[6];
    #pragma unroll
    for (int m = 0; m < 6; ++m) { af[m] = b_g[c]; ag[m] = b_g[COUT_ + c]; }
    for (int j = 0; j < COUT_; ++j) {
      float wf0 = WgT[(3*j+0)*128 + c],      wf1 = WgT[(3*j+1)*128 + c],      wf2 = WgT[(3*j+2)*128 + c];
      float wg0 = WgT[(3*j+0)*128 + 64 + c], wg1 = WgT[(3*j+1)*128 + 64 + c], wg2 = WgT[(3*j+2)*128 + 64 + c];
      #pragma unroll
      for (int m = 0; m < 6; ++m) {
        int t = tq + 4*m;
        float xs = XSs[j*T_ + t], y1 = Y1s[j*T_ + t], y2 = Y2s[j*T_ + t];
        af[m] += wf0 * xs + wf1 * y1 + wf2 * y2;
        ag[m] += wg0 * xs + wg1 * y1 + wg2 * y2;
      }
    }
    #pragma unroll
    for (int m = 0; m < 6; ++m) {
      int t = tq + 4*m;
      float g = sigm_(ag[m]);
      out[(((size_t)b * COUT_ + c) * N_ + n) * T_ + t] = (af[m] + x1sh[c*T_ + t]) * g;
    }
  }
}

// ---------------------------------------------------------------------------
extern "C" void kernel_launch(void* const* d_in, const int* in_sizes, int n_in,
                              void* d_out, int out_size, void* d_ws, size_t ws_size,
                              hipStream_t stream) {
  const float* x        = (const float*)d_in[0];
  const float* supports = (const float*)d_in[1];
  const float* CD       = (const float*)d_in[2];
  const float* CS       = (const float*)d_in[3];
  const float* adj      = (const float*)d_in[4];
  const float* W_de  = (const float*)d_in[5];  const float* b_de  = (const float*)d_in[6];
  const float* Wd    = (const float*)d_in[7];
  const float* W_pro = (const float*)d_in[8];  const float* b_pro = (const float*)d_in[9];
  const float* W_mii = (const float*)d_in[10]; const float* b_mii = (const float*)d_in[11];
  const float* W_1   = (const float*)d_in[12]; const float* b_1   = (const float*)d_in[13];
  const float* Wq_t  = (const float*)d_in[14]; const float* bq_t  = (const float*)d_in[15];
  const float* Wk_t  = (const float*)d_in[16]; const float* bk_t  = (const float*)d_in[17];
  const float* Wv_t  = (const float*)d_in[18]; const float* bv_t  = (const float*)d_in[19];
  const float* W_c1  = (const float*)d_in[20]; const float* b_c1  = (const float*)d_in[21];
  const float* Wq_s  = (const float*)d_in[22]; const float* bq_s  = (const float*)d_in[23];
  const float* Wk_s  = (const float*)d_in[24]; const float* bk_s  = (const float*)d_in[25];
  const float* Wv_s  = (const float*)d_in[26]; const float* bv_s  = (const float*)d_in[27];
  const float* W_g   = (const float*)d_in[28]; const float* b_g   = (const float*)d_in[29];
  float* out = (float*)d_out;

  char* ws = (char*)d_ws;
  float*    delay = (float*)(ws + OFF_DELAY);
  float*    Mbuf  = (float*)(ws + OFF_M);
  float*    Rbuf  = (float*)(ws + OFF_R);
  float*    u     = (float*)(ws + OFF_U);
  float*    W1T   = (float*)(ws + OFF_W1T);
  float*    WgT   = (float*)(ws + OFF_WGT);
  ushort_t* Sbf   = (ushort_t*)(ws + OFF_SBF);
  ushort_t* adjbf = (ushort_t*)(ws + OFF_ADJBF);
  ushort_t* STbf  = (ushort_t*)(ws + OFF_STBF);
  ushort_t* L2bf  = (ushort_t*)(ws + OFF_L2BF);
  ushort_t* Ue    = (ushort_t*)(ws + OFF_X1);
  ushort_t* P     = (ushort_t*)(ws + OFF_X1);   // overwrites Ue (dead)
  ushort_t* UeT   = (ushort_t*)(ws + OFF_X2);
  ushort_t* XST   = (ushort_t*)(ws + OFF_X2);   // overwrites UeT (dead)
  ushort_t* XS    = (ushort_t*)(ws + OFF_XS);
  ushort_t* Y1h   = (ushort_t*)(ws + OFF_Y1H);
  ushort_t* Y2h   = (ushort_t*)(ws + OFF_Y2H);
  ushort_t* WBF   = (ushort_t*)(ws + OFF_WBF);

  (void)in_sizes; (void)n_in; (void)out_size; (void)ws_size;

  // 1) conversions + weight prep
  k_prep<<<dim3((PREP_TOTAL + 255)/256), 256, 0, stream>>>(
      supports, adj, W_de, Wq_t, W_1, W_mii, Wk_t, Wv_t, Wq_s, Wk_s, Wv_s,
      W_c1, W_g, Sbf, adjbf, STbf, W1T, WgT, WBF);
  // 2) delay / Mbuf / Rbuf
  k_pre<<<dim3((NT_ + N_*COUT_ + N_ + 255)/256), 256, 0, stream>>>(
      CD, Wd, CS, W_mii, adj, delay, Mbuf, Rbuf);
  // 3) L2 = 2*S@S - I
  k_mmx<2><<<dim3(8, 8), 256, 0, stream>>>(Sbf, STbf, L2bf, 1024);
  // 4) u + Ue
  k_u<<<dim3((BNT_ + 255)/256), 256, 0, stream>>>(x, W_pro, b_pro, CS, u, Ue);
  // 5) UeT
  k_tr<<<dim3(UE_COLS/32, N_/32), 256, 0, stream>>>(Ue, UeT, N_, UE_COLS);
  // 6) P = adj @ Ue
  k_mmx<0><<<dim3(UE_COLS/128, N_/128), 256, 0, stream>>>(adjbf, UeT, P, UE_COLS);
  // 7) MFMA attention pipeline -> XS
  k_attn_mfma<<<dim3(N_, B_), 256, 0, stream>>>(
      x, delay, Mbuf, Rbuf, u, P, WBF,
      b_de, bq_t, b_1, b_mii, bk_t, bv_t, bq_s, bk_s, bv_s, b_c1, XS);
  // 8) per half: transpose, Y1 = S@XS, Y2 = L2@XS, final
  for (int h = 0; h < 2; ++h) {
    k_tr<<<dim3(HALF_COLS/32, N_/32), 256, 0, stream>>>(
        XS + (size_t)h * HALF_COLS, XST, N_, XS_COLS);
    k_mmx<0><<<dim3(HALF_COLS/128, N_/128), 256, 0, stream>>>(Sbf, XST, Y1h, HALF_COLS);
    k_mmx<0><<<dim3(HALF_COLS/128, N_/128), 256, 0, stream>>>(L2bf, XST, Y2h, HALF_COLS);
    k_final<<<dim3(N_, 8), 256, 0, stream>>>(
        x, XS, Y1h, Y2h, W1T, b_1, WgT, b_g, h, out);
  }
}